// Round 1
// baseline (6677.031 us; speedup 1.0000x reference)
//
#include <hip/hip_runtime.h>

#define N_USERS 1000000
#define NEDGE   32000000
#define OUT_F   64
#define BN_EPS  1e-5f

// Zero the 4 hop-result arrays in workspace (harness poisons ws with 0xAA).
__global__ void zero_kernel(float* __restrict__ p, int n) {
    int i = blockIdx.x * blockDim.x + threadIdx.x;
    int stride = gridDim.x * blockDim.x;
    for (; i < n; i += stride) p[i] = 0.0f;
}

// One hop: nxt[dst[e]] += cur[src[e]] * ew[e], 4 edges per thread (vectorized
// sequential loads of src/dst/ew; gather + atomic scatter on 4MB vectors).
__global__ __launch_bounds__(256) void hop_kernel(
    const int* __restrict__ src, const int* __restrict__ dst,
    const float* __restrict__ ew, const float* __restrict__ cur,
    float* __restrict__ nxt) {
    int e = blockIdx.x * blockDim.x + threadIdx.x;   // group of 4 edges
    if (e * 4 < NEDGE) {
        int4   s = ((const int4*)src)[e];
        int4   d = ((const int4*)dst)[e];
        float4 w = ((const float4*)ew)[e];
        atomicAdd(&nxt[d.x], cur[s.x] * w.x);
        atomicAdd(&nxt[d.y], cur[s.y] * w.y);
        atomicAdd(&nxt[d.z], cur[s.z] * w.z);
        atomicAdd(&nxt[d.w], cur[s.w] * w.w);
    }
}

// One wave (64 lanes) per node: lane o computes y[n,o] = bias[o] + sum_k c_k*W[o,k],
// then wave-wide mean/var (BatchNorm1d over the 64 features), BN affine, store.
__global__ __launch_bounds__(256) void finalize_kernel(
    const float* __restrict__ x,  const float* __restrict__ f1,
    const float* __restrict__ f2, const float* __restrict__ f3,
    const float* __restrict__ f4, const float* __restrict__ W,
    const float* __restrict__ bias, const float* __restrict__ gamma,
    const float* __restrict__ beta, float* __restrict__ out) {
    int lane = threadIdx.x & 63;
    int waveInBlock = threadIdx.x >> 6;
    int wavesPerBlock = blockDim.x >> 6;
    int gwave  = blockIdx.x * wavesPerBlock + waveInBlock;
    int nwaves = gridDim.x * wavesPerBlock;

    // weight is [OUT_F, K, IN_F] = [64,5,1] row-major: W[o*5 + k]
    float w0 = W[lane * 5 + 0];
    float w1 = W[lane * 5 + 1];
    float w2 = W[lane * 5 + 2];
    float w3 = W[lane * 5 + 3];
    float w4 = W[lane * 5 + 4];
    float b  = bias[lane];

    for (int n = gwave; n < N_USERS; n += nwaves) {
        float c0 = x[n], c1 = f1[n], c2 = f2[n], c3 = f3[n], c4 = f4[n];
        float y = b + c0 * w0 + c1 * w1 + c2 * w2 + c3 * w3 + c4 * w4;

        // mean over the 64 features (one wave)
        float s = y;
        #pragma unroll
        for (int off = 32; off; off >>= 1) s += __shfl_xor(s, off);
        float mean = s * (1.0f / 64.0f);

        float d = y - mean;
        float v = d * d;
        #pragma unroll
        for (int off = 32; off; off >>= 1) v += __shfl_xor(v, off);
        float var = v * (1.0f / 64.0f);

        float o = d * rsqrtf(var + BN_EPS) * gamma[n] + beta[n];
        out[(size_t)n * OUT_F + lane] = o;
    }
}

extern "C" void kernel_launch(void* const* d_in, const int* in_sizes, int n_in,
                              void* d_out, int out_size, void* d_ws, size_t ws_size,
                              hipStream_t stream) {
    const float* x     = (const float*)d_in[0];
    const int*   ei    = (const int*)d_in[1];
    const float* ew    = (const float*)d_in[2];
    const float* W     = (const float*)d_in[3];
    const float* bias  = (const float*)d_in[4];
    const float* gamma = (const float*)d_in[5];
    const float* beta  = (const float*)d_in[6];
    float* out = (float*)d_out;

    float* f = (float*)d_ws;              // 4 hop results, N floats each (16 MB)
    const int* src = ei;                  // edge_index[0]
    const int* dst = ei + NEDGE;          // edge_index[1]

    zero_kernel<<<4096, 256, 0, stream>>>(f, 4 * N_USERS);

    const float* cur = x;
    for (int h = 0; h < 4; ++h) {
        float* nxt = f + (size_t)h * N_USERS;
        hop_kernel<<<NEDGE / 4 / 256, 256, 0, stream>>>(src, dst, ew, cur, nxt);
        cur = nxt;
    }

    finalize_kernel<<<2048, 256, 0, stream>>>(
        x, f, f + N_USERS, f + 2 * N_USERS, f + 3 * N_USERS,
        W, bias, gamma, beta, out);
}

// Round 2
// 2130.785 us; speedup vs baseline: 3.1336x; 3.1336x over previous
//
#include <hip/hip_runtime.h>

#define N_USERS 1000000
#define NEDGE   32000000
#define OUT_F   64
#define BN_EPS  1e-5f

// Destination binning geometry
#define SBITS     10
#define S_BUCKET  1024                     // nodes per bucket
#define NB        977                      // ceil(N_USERS / S_BUCKET)
#define CAP       36864                    // per-bucket record capacity (mean 32768 + 22 sigma)
#define SCAT_BLOCKS 512
#define CHUNK     (NEDGE / SCAT_BLOCKS)    // 62500

// ---------------- binned path ----------------

__global__ void init_cursors(unsigned* __restrict__ cursors) {
    int i = blockIdx.x * blockDim.x + threadIdx.x;
    if (i < NB) cursors[i] = (unsigned)i * CAP;
}

// Partition edges by destination bucket. Per block: LDS histogram of its chunk,
// one global atomicAdd per non-empty bucket to reserve a contiguous range, then
// scatter packed 8B records (meta = dst_local<<20 | src, weight bits).
__global__ __launch_bounds__(256) void scatter_bin(
    const int* __restrict__ src, const int* __restrict__ dst,
    const float* __restrict__ ew, uint2* __restrict__ rec,
    unsigned* __restrict__ cursors) {
    __shared__ unsigned cnt[NB];
    __shared__ unsigned base[NB];
    int tid = threadIdx.x;
    int start = blockIdx.x * CHUNK;
    int end = start + CHUNK;

    for (int i = tid; i < NB; i += 256) cnt[i] = 0;
    __syncthreads();
    for (int i = start + tid; i < end; i += 256)
        atomicAdd(&cnt[dst[i] >> SBITS], 1u);
    __syncthreads();
    for (int i = tid; i < NB; i += 256) {
        unsigned c = cnt[i];
        base[i] = c ? atomicAdd(&cursors[i], c) : 0u;
    }
    __syncthreads();
    for (int i = tid; i < NB; i += 256) cnt[i] = 0;
    __syncthreads();
    for (int i = start + tid; i < end; i += 256) {
        int d = dst[i];
        int b = d >> SBITS;
        unsigned p = base[b] + atomicAdd(&cnt[b], 1u);
        unsigned meta = ((unsigned)(d & (S_BUCKET - 1)) << 20) | (unsigned)src[i];
        rec[p] = make_uint2(meta, __float_as_uint(ew[i]));
    }
}

// One block per destination bucket: accumulate messages into a 4KB LDS array
// (fast ds_add_f32, no device-scope atomics), then one coalesced store.
__global__ __launch_bounds__(256) void hop_bucket(
    const uint2* __restrict__ rec, const unsigned* __restrict__ cursors,
    const float* __restrict__ cur, float* __restrict__ nxt) {
    __shared__ float acc[S_BUCKET];
    int tid = threadIdx.x;
    int b = blockIdx.x;
    for (int i = tid; i < S_BUCKET; i += 256) acc[i] = 0.0f;
    __syncthreads();
    unsigned start = (unsigned)b * CAP;
    unsigned end = cursors[b];   // final cursor = start + bucket count
    for (unsigned i = start + tid; i < end; i += 256) {
        uint2 r = rec[i];
        float m = cur[r.x & 0xFFFFFu] * __uint_as_float(r.y);
        atomicAdd(&acc[r.x >> 20], m);
    }
    __syncthreads();
    int nb0 = b << SBITS;
    for (int i = tid; i < S_BUCKET; i += 256) {
        int n = nb0 + i;
        if (n < N_USERS) nxt[n] = acc[i];
    }
}

// ---------------- fallback path (round-1, device atomics) ----------------

__global__ void zero_kernel(float* __restrict__ p, int n) {
    int i = blockIdx.x * blockDim.x + threadIdx.x;
    int stride = gridDim.x * blockDim.x;
    for (; i < n; i += stride) p[i] = 0.0f;
}

__global__ __launch_bounds__(256) void hop_atomic(
    const int* __restrict__ src, const int* __restrict__ dst,
    const float* __restrict__ ew, const float* __restrict__ cur,
    float* __restrict__ nxt) {
    int e = blockIdx.x * blockDim.x + threadIdx.x;
    if (e * 4 < NEDGE) {
        int4   s = ((const int4*)src)[e];
        int4   d = ((const int4*)dst)[e];
        float4 w = ((const float4*)ew)[e];
        atomicAdd(&nxt[d.x], cur[s.x] * w.x);
        atomicAdd(&nxt[d.y], cur[s.y] * w.y);
        atomicAdd(&nxt[d.z], cur[s.z] * w.z);
        atomicAdd(&nxt[d.w], cur[s.w] * w.w);
    }
}

// ---------------- finalize: 5->64 matvec + BatchNorm over features ----------------

__global__ __launch_bounds__(256) void finalize_kernel(
    const float* __restrict__ x,  const float* __restrict__ f1,
    const float* __restrict__ f2, const float* __restrict__ f3,
    const float* __restrict__ f4, const float* __restrict__ W,
    const float* __restrict__ bias, const float* __restrict__ gamma,
    const float* __restrict__ beta, float* __restrict__ out) {
    int lane = threadIdx.x & 63;
    int waveInBlock = threadIdx.x >> 6;
    int wavesPerBlock = blockDim.x >> 6;
    int gwave  = blockIdx.x * wavesPerBlock + waveInBlock;
    int nwaves = gridDim.x * wavesPerBlock;

    float w0 = W[lane * 5 + 0];
    float w1 = W[lane * 5 + 1];
    float w2 = W[lane * 5 + 2];
    float w3 = W[lane * 5 + 3];
    float w4 = W[lane * 5 + 4];
    float b  = bias[lane];

    for (int n = gwave; n < N_USERS; n += nwaves) {
        float c0 = x[n], c1 = f1[n], c2 = f2[n], c3 = f3[n], c4 = f4[n];
        float y = b + c0 * w0 + c1 * w1 + c2 * w2 + c3 * w3 + c4 * w4;

        float s = y;
        #pragma unroll
        for (int off = 32; off; off >>= 1) s += __shfl_xor(s, off);
        float mean = s * (1.0f / 64.0f);

        float d = y - mean;
        float v = d * d;
        #pragma unroll
        for (int off = 32; off; off >>= 1) v += __shfl_xor(v, off);
        float var = v * (1.0f / 64.0f);

        float o = d * rsqrtf(var + BN_EPS) * gamma[n] + beta[n];
        out[(size_t)n * OUT_F + lane] = o;
    }
}

extern "C" void kernel_launch(void* const* d_in, const int* in_sizes, int n_in,
                              void* d_out, int out_size, void* d_ws, size_t ws_size,
                              hipStream_t stream) {
    const float* x     = (const float*)d_in[0];
    const int*   ei    = (const int*)d_in[1];
    const float* ew    = (const float*)d_in[2];
    const float* W     = (const float*)d_in[3];
    const float* bias  = (const float*)d_in[4];
    const float* gamma = (const float*)d_in[5];
    const float* beta  = (const float*)d_in[6];
    float* out = (float*)d_out;

    const int* src = ei;
    const int* dst = ei + NEDGE;

    // Workspace layout
    float* f = (float*)d_ws;                           // 4*N floats (16 MB)
    uint2* rec = (uint2*)(f + 4ull * N_USERS);         // NB*CAP records (288 MB)
    unsigned* cursors = (unsigned*)(rec + (size_t)NB * CAP);
    size_t needed = 4ull * N_USERS * 4 + (size_t)NB * CAP * 8 + (size_t)NB * 4;

    if (ws_size >= needed) {
        init_cursors<<<(NB + 255) / 256, 256, 0, stream>>>(cursors);
        scatter_bin<<<SCAT_BLOCKS, 256, 0, stream>>>(src, dst, ew, rec, cursors);
        const float* cur = x;
        for (int h = 0; h < 4; ++h) {
            float* nxt = f + (size_t)h * N_USERS;
            hop_bucket<<<NB, 256, 0, stream>>>(rec, cursors, cur, nxt);
            cur = nxt;
        }
    } else {
        zero_kernel<<<4096, 256, 0, stream>>>(f, 4 * N_USERS);
        const float* cur = x;
        for (int h = 0; h < 4; ++h) {
            float* nxt = f + (size_t)h * N_USERS;
            hop_atomic<<<NEDGE / 4 / 256, 256, 0, stream>>>(src, dst, ew, cur, nxt);
            cur = nxt;
        }
    }

    finalize_kernel<<<2048, 256, 0, stream>>>(
        x, f, f + N_USERS, f + 2 * N_USERS, f + 3 * N_USERS,
        W, bias, gamma, beta, out);
}